// Round 8
// baseline (116.549 us; speedup 1.0000x reference)
//
#include <hip/hip_runtime.h>

#define TT 64
#define DIM 13
#define NSEQ 128
#define NWAVE 2080           // sum over a of ceil((127-a)/4): 4 partners per wave, shared a
#define INFV 1e10f
#define C_EXP 14.4269504088896f     // log2(e)/gamma ; S = R*C_EXP (scaled log2 domain)
#define C_INV 0.06931471805599453f  // gamma*ln2

typedef _Float16 h2 __attribute__((ext_vector_type(2)));

__device__ __forceinline__ float fdot2(h2 a, h2 b, float c) {
    return __builtin_amdgcn_fdot2(a, b, c, false);
}
__device__ __forceinline__ h2 mkh2(float a, float b) {
    h2 p; p.x = (_Float16)a; p.y = (_Float16)b; return p;
}
__device__ __forceinline__ h2 bch2(unsigned u) { return __builtin_bit_cast(h2, u); }
// lane i <- lane i-1, lane 0 <- INFV (v_mov_b32 dpp wave_shr:1, full-rate VALU)
__device__ __forceinline__ float shr1_inf(float x) {
    int r = __builtin_amdgcn_update_dpp(__builtin_bit_cast(int, INFV),
                                        __builtin_bit_cast(int, x),
                                        0x138, 0xf, 0xf, false);
    return __builtin_bit_cast(float, r);
}
__device__ __forceinline__ int Tq4(int N) {   // sum_{n=1..N} ceil(n/4)
    int q = N >> 2, r = N & 3;
    return 2 * q * (q + 1) + r * (q + 1);
}
// one softmin+update step for a single chain (S, d are in/out)
__device__ __forceinline__ void chain_step(float& S, float& d, float lf, float acc) {
    float m  = fminf(fminf(S, lf), d);                 // -> v_min3_f32
    float md = __builtin_amdgcn_fmed3f(S, lf, d);
    float M  = fmaxf(fmaxf(S, lf), d);                 // -> v_max3_f32
    float s  = 1.0f + __builtin_amdgcn_exp2f(m - md) + __builtin_amdgcn_exp2f(m - M);
    S = fmaf(acc, C_EXP, m - __builtin_amdgcn_logf(s));   // v_log_f32 = log2
    d = lf;
}

__global__ __launch_bounds__(256, 4) void sdtw_pairs(const float* __restrict__ xxx,
                                                     const float* __restrict__ yyy,
                                                     float* __restrict__ simR) {
    // component-major x-tile: [7 comps][4 waves][64 rows] dwords; anti-diagonal
    // b32 reads are 2-way bank-aliased = free.
    __shared__ unsigned xl[7 * 4 * TT];
    const int wave = threadIdx.x >> 6;
    const int lane = threadIdx.x & 63;
    const int t = blockIdx.x * 4 + wave;          // wave id 0..2079

    // decode t -> (a, q): waves before row a = NWAVE - Tq4(127-a)
    int a = 127 - (int)sqrtf(8.0f * (float)(NWAVE - t));
    if (a < 0) a = 0;
    if (a > 126) a = 126;
    while (NWAVE - Tq4(127 - a) > t) a--;
    while (a < 126 && NWAVE - Tq4(127 - (a + 1)) <= t) a++;
    const int q = t - (NWAVE - Tq4(127 - a));
    const int b0 = a + 1 + 4 * q;
    const int bA = b0;                              // clamped dups recompute bA's pair;
    const int bB = (b0 + 1 < 128) ? b0 + 1 : 127;   // same value lands at same simR slot
    const int bC = (b0 + 2 < 128) ? b0 + 2 : 127;
    const int bD = (b0 + 3 < 128) ? b0 + 3 : 127;

    // lane = column j: y_j of the 4 partner sequences in registers
    h2 yA[7], yB[7], yC[7], yD[7];
    float sqA = 0.f, sqB = 0.f, sqC = 0.f, sqD = 0.f;
    {
        const float* fA = ((bA < 64) ? xxx + (size_t)bA * TT * DIM : yyy + (size_t)(bA - 64) * TT * DIM) + lane * DIM;
        const float* fB = ((bB < 64) ? xxx + (size_t)bB * TT * DIM : yyy + (size_t)(bB - 64) * TT * DIM) + lane * DIM;
        const float* fC = ((bC < 64) ? xxx + (size_t)bC * TT * DIM : yyy + (size_t)(bC - 64) * TT * DIM) + lane * DIM;
        const float* fD = ((bD < 64) ? xxx + (size_t)bD * TT * DIM : yyy + (size_t)(bD - 64) * TT * DIM) + lane * DIM;
        float vA[DIM], vB[DIM], vC[DIM], vD[DIM];
#pragma unroll
        for (int c = 0; c < DIM; c++) {
            vA[c] = fA[c]; sqA += vA[c] * vA[c];
            vB[c] = fB[c]; sqB += vB[c] * vB[c];
            vC[c] = fC[c]; sqC += vC[c] * vC[c];
            vD[c] = fD[c]; sqD += vD[c] * vD[c];
        }
#pragma unroll
        for (int c = 0; c < 6; c++) {
            yA[c] = mkh2(vA[2 * c], vA[2 * c + 1]);
            yB[c] = mkh2(vB[2 * c], vB[2 * c + 1]);
            yC[c] = mkh2(vC[2 * c], vC[2 * c + 1]);
            yD[c] = mkh2(vD[2 * c], vD[2 * c + 1]);
        }
        yA[6] = mkh2(vA[12], 1.0f);
        yB[6] = mkh2(vB[12], 1.0f);
        yC[6] = mkh2(vC[12], 1.0f);
        yD[6] = mkh2(vD[12], 1.0f);
    }

    // x side (seq a, shared by all 4 pairs): (-2x) pairs, last (-2x12, sqx)
    {
        const float* fx = ((a < 64) ? xxx + (size_t)a * TT * DIM : yyy + (size_t)(a - 64) * TT * DIM) + lane * DIM;
        float xv[DIM], sqx = 0.f;
#pragma unroll
        for (int c = 0; c < DIM; c++) { xv[c] = fx[c]; sqx += xv[c] * xv[c]; }
        unsigned* row = xl + wave * TT + lane;
#pragma unroll
        for (int c = 0; c < 6; c++)
            row[c * 256] = __builtin_bit_cast(unsigned, mkh2(-2.f * xv[2 * c], -2.f * xv[2 * c + 1]));
        row[6 * 256] = __builtin_bit_cast(unsigned, mkh2(-2.f * xv[12], sqx));
    }
    __syncthreads();

    // Four interleaved DPs sharing one x-stream. Lane j at step k: cell (k-j, j).
    // up = own prev S; left = wave_shr:1(S) (INFV at lane 0); diag = prev left.
    // No validity predicates: inactive lanes ride at ~INFV; exp2 terms underflow.
    const unsigned* xw = xl + wave * TT;
    float SA = INFV, SB = INFV, SC = INFV, SD = INFV;
    const float ini = (lane == 0) ? 0.f : INFV;
    float dA = ini, dB = ini, dC = ini, dD = ini;
    int jc = (-lane) & (TT - 1);

#pragma unroll 2
    for (int k = 0; k < 2 * TT - 1; k++) {
        unsigned w0 = xw[jc];
        unsigned w1 = xw[jc + 1 * 256];
        unsigned w2 = xw[jc + 2 * 256];
        unsigned w3 = xw[jc + 3 * 256];
        unsigned w4 = xw[jc + 4 * 256];
        unsigned w5 = xw[jc + 5 * 256];
        unsigned w6 = xw[jc + 6 * 256];
        jc = (jc + 1) & (TT - 1);

        float aA = sqA, aB = sqB, aC = sqC, aD = sqD;
        aA = fdot2(yA[0], bch2(w0), aA); aB = fdot2(yB[0], bch2(w0), aB);
        aC = fdot2(yC[0], bch2(w0), aC); aD = fdot2(yD[0], bch2(w0), aD);
        aA = fdot2(yA[1], bch2(w1), aA); aB = fdot2(yB[1], bch2(w1), aB);
        aC = fdot2(yC[1], bch2(w1), aC); aD = fdot2(yD[1], bch2(w1), aD);
        aA = fdot2(yA[2], bch2(w2), aA); aB = fdot2(yB[2], bch2(w2), aB);
        aC = fdot2(yC[2], bch2(w2), aC); aD = fdot2(yD[2], bch2(w2), aD);
        aA = fdot2(yA[3], bch2(w3), aA); aB = fdot2(yB[3], bch2(w3), aB);
        aC = fdot2(yC[3], bch2(w3), aC); aD = fdot2(yD[3], bch2(w3), aD);
        aA = fdot2(yA[4], bch2(w4), aA); aB = fdot2(yB[4], bch2(w4), aB);
        aC = fdot2(yC[4], bch2(w4), aC); aD = fdot2(yD[4], bch2(w4), aD);
        aA = fdot2(yA[5], bch2(w5), aA); aB = fdot2(yB[5], bch2(w5), aB);
        aC = fdot2(yC[5], bch2(w5), aC); aD = fdot2(yD[5], bch2(w5), aD);
        aA = fdot2(yA[6], bch2(w6), aA); aB = fdot2(yB[6], bch2(w6), aB);
        aC = fdot2(yC[6], bch2(w6), aC); aD = fdot2(yD[6], bch2(w6), aD);

        float lA = shr1_inf(SA);
        float lB = shr1_inf(SB);
        float lC = shr1_inf(SC);
        float lD = shr1_inf(SD);

        chain_step(SA, dA, lA, aA);
        chain_step(SB, dB, lB, aB);
        chain_step(SC, dC, lC, aC);
        chain_step(SD, dD, lD, aD);
    }

    if (lane == 63) {
        const float rA = SA * C_INV;
        const float rB = SB * C_INV;
        const float rC = SC * C_INV;
        const float rD = SD * C_INV;
        simR[a * NSEQ + bA] = rA; simR[bA * NSEQ + a] = rA;
        simR[a * NSEQ + bB] = rB; simR[bB * NSEQ + a] = rB;
        simR[a * NSEQ + bC] = rC; simR[bC * NSEQ + a] = rC;
        simR[a * NSEQ + bD] = rD; simR[bD * NSEQ + a] = rD;
    }
}

// one wave per row: lse(row) - positive ; result parked in the (unused) diagonal
__global__ void row_lse(float* __restrict__ simR) {
    const int r = blockIdx.x;
    const int lane = threadIdx.x;
    const float* rowp = simR + r * NSEQ;
    float v0 = (lane == r) ? 0.f : 2.f * rowp[lane];
    const int c1 = lane + 64;
    float v1 = (c1 == r) ? 0.f : 2.f * rowp[c1];
    float mx = fmaxf(v0, v1);
#pragma unroll
    for (int o = 32; o; o >>= 1) mx = fmaxf(mx, __shfl_xor(mx, o));
    float s = __builtin_amdgcn_exp2f((v0 - mx) * 1.4426950408889634f)
            + __builtin_amdgcn_exp2f((v1 - mx) * 1.4426950408889634f);
#pragma unroll
    for (int o = 32; o; o >>= 1) s += __shfl_xor(s, o);
    if (lane == 0) {
        const int i = r & 63;
        float pos = 2.f * simR[i * NSEQ + i + 64];
        simR[r * NSEQ + r] = mx + 0.6931471805599453f * __builtin_amdgcn_logf(s) - pos;
    }
}

__global__ void final_loss(const float* __restrict__ simR, float* __restrict__ out) {
    __shared__ float red[NSEQ];
    const int tid = threadIdx.x;
    red[tid] = simR[tid * NSEQ + tid];
    __syncthreads();
    if (tid == 0) {
        float tsum = 0.f;
        for (int c = 0; c < NSEQ; c++) tsum += red[c];
        out[0] = tsum / (float)NSEQ;
    }
}

extern "C" void kernel_launch(void* const* d_in, const int* in_sizes, int n_in,
                              void* d_out, int out_size, void* d_ws, size_t ws_size,
                              hipStream_t stream) {
    const float* xxx = (const float*)d_in[0];
    const float* yyy = (const float*)d_in[1];
    float* out = (float*)d_out;
    float* simR = (float*)d_ws;   // 16384 floats = 64 KB

    sdtw_pairs<<<NWAVE / 4, 256, 0, stream>>>(xxx, yyy, simR);
    row_lse<<<NSEQ, 64, 0, stream>>>(simR);
    final_loss<<<1, NSEQ, 0, stream>>>(simR, out);
}

// Round 9
// 42.083 us; speedup vs baseline: 2.7695x; 2.7695x over previous
//
#include <hip/hip_runtime.h>

#define TT 64
#define DIM 13
#define NSEQ 128
#define NPAIRS 8128          // 128*127/2 upper-triangle pairs (soft-DTW symmetric)
#define NWAVE 4064           // 2 pairs per wave (one per 32-lane half)
#define NSTEP (TT + 32 - 1)  // 95 anti-diagonal steps (32 lane-columns x 64 rows)
#define INFV 1e10f
#define C_EXP 14.4269504088896f     // log2(e)/gamma ; S = R*C_EXP (scaled log2 domain)
#define C_INV 0.06931471805599453f  // gamma*ln2

typedef _Float16 h2 __attribute__((ext_vector_type(2)));

__device__ __forceinline__ float fdot2(h2 a, h2 b, float c) {
    return __builtin_amdgcn_fdot2(a, b, c, false);
}
__device__ __forceinline__ h2 mkh2(float a, float b) {
    h2 p; p.x = (_Float16)a; p.y = (_Float16)b; return p;
}
__device__ __forceinline__ h2 bch2(unsigned u) { return __builtin_bit_cast(h2, u); }
// lane i <- lane i-1 (wave_shr:1), lane 0 <- INFV; full-rate VALU, no DS op
__device__ __forceinline__ float shr1_inf(float x) {
    int r = __builtin_amdgcn_update_dpp(__builtin_bit_cast(int, INFV),
                                        __builtin_bit_cast(int, x),
                                        0x138, 0xf, 0xf, false);
    return __builtin_bit_cast(float, r);
}
// one softmin+update: S <- C*acc + softmin(S, lf, dg) in scaled-log2 domain
__device__ __forceinline__ float smstep(float S, float lf, float dg, float acc) {
    float m  = fminf(fminf(S, lf), dg);                 // v_min3_f32
    float md = __builtin_amdgcn_fmed3f(S, lf, dg);
    float M  = fmaxf(fmaxf(S, lf), dg);                 // v_max3_f32
    float s  = 1.0f + __builtin_amdgcn_exp2f(m - md) + __builtin_amdgcn_exp2f(m - M);
    return fmaf(acc, C_EXP, m - __builtin_amdgcn_logf(s));   // v_log_f32 = log2
}

__global__ __launch_bounds__(256) void sdtw_pairs(const float* __restrict__ xxx,
                                                  const float* __restrict__ yyy,
                                                  float* __restrict__ simR) {
    // Per wave: 2 pairs (lane halves). Lane (half, sj) owns DP columns 2sj, 2sj+1
    // of its half's pair. x staged comp-major: [7 comps][2 halves * 64 rows].
    __shared__ unsigned xl[4][7 * 2 * TT];
    const int wave = threadIdx.x >> 6;
    const int lane = threadIdx.x & 63;
    const int half = lane >> 5;
    const int sj   = lane & 31;
    const int p = 2 * (blockIdx.x * 4 + wave) + half;   // pair id 0..8127

    // decode p -> (a,b), a<b ; pairs before row a: a*(255-a)/2
    int a = (int)((255.0f - sqrtf(65025.0f - 8.0f * (float)p)) * 0.5f);
    if (a < 0) a = 0;
    if (a > 126) a = 126;
    while (a * (255 - a) / 2 > p) a--;
    while ((a + 1) * (254 - a) / 2 <= p) a++;
    const int b = a + 1 + (p - a * (255 - a) / 2);

    // y side: columns 2sj, 2sj+1 of seq b, in registers
    h2 yA[7], yB[7];
    float sqyA = 0.f, sqyB = 0.f;
    {
        const float* fb = ((b < 64) ? xxx + (size_t)b * TT * DIM
                                    : yyy + (size_t)(b - 64) * TT * DIM) + (2 * sj) * DIM;
        float vA[DIM], vB[DIM];
#pragma unroll
        for (int c = 0; c < DIM; c++) {
            vA[c] = fb[c];        sqyA += vA[c] * vA[c];
            vB[c] = fb[DIM + c];  sqyB += vB[c] * vB[c];
        }
#pragma unroll
        for (int c = 0; c < 6; c++) {
            yA[c] = mkh2(vA[2 * c], vA[2 * c + 1]);
            yB[c] = mkh2(vB[2 * c], vB[2 * c + 1]);
        }
        yA[6] = mkh2(vA[12], 1.0f);
        yB[6] = mkh2(vB[12], 1.0f);
    }

    // x side (seq a): rows sj and sj+32 staged; pairs (-2x), last (-2x12, sqx)
    {
        const float* fa = (a < 64) ? xxx + (size_t)a * TT * DIM
                                   : yyy + (size_t)(a - 64) * TT * DIM;
        unsigned* xw = xl[wave];
#pragma unroll
        for (int rr = 0; rr < 2; rr++) {
            const int r = sj + 32 * rr;
            const float* fx = fa + r * DIM;
            float xv[DIM], sqx = 0.f;
#pragma unroll
            for (int c = 0; c < DIM; c++) { xv[c] = fx[c]; sqx += xv[c] * xv[c]; }
            unsigned* dst = xw + half * TT + r;
#pragma unroll
            for (int c = 0; c < 6; c++)
                dst[c * 128] = __builtin_bit_cast(unsigned, mkh2(-2.f * xv[2 * c], -2.f * xv[2 * c + 1]));
            dst[6 * 128] = __builtin_bit_cast(unsigned, mkh2(-2.f * xv[12], sqx));
        }
    }
    __syncthreads();

    // DP: at step k, lane computes cells (i, 2sj) and (i, 2sj+1), i = k - sj.
    //   A: up = own SA; left = lane-1's SB (prev step) via dpp; diag = prev left.
    //   B: up = own SB; left = SA (just computed); diag = SA before update. No shuffle.
    // No validity predicates: inactive lanes ride at ~INFV; exp2 terms underflow;
    // post-valid garbage (wrapped x rows) only ever feeds invalid cells.
    const unsigned* xp = xl[wave] + half * TT;
    float SA = INFV, SB = INFV;
    float dgA = (sj == 0) ? 0.f : INFV;     // corner for cell (0,0)
    const bool col0 = (sj == 0);
    int ic = (-sj) & (TT - 1);

#pragma unroll 2
    for (int k = 0; k < NSTEP; k++) {
        unsigned w0 = xp[ic];
        unsigned w1 = xp[ic + 1 * 128];
        unsigned w2 = xp[ic + 2 * 128];
        unsigned w3 = xp[ic + 3 * 128];
        unsigned w4 = xp[ic + 4 * 128];
        unsigned w5 = xp[ic + 5 * 128];
        unsigned w6 = xp[ic + 6 * 128];
        ic = (ic + 1) & (TT - 1);

        float aA = sqyA, aB = sqyB;
        aA = fdot2(yA[0], bch2(w0), aA); aB = fdot2(yB[0], bch2(w0), aB);
        aA = fdot2(yA[1], bch2(w1), aA); aB = fdot2(yB[1], bch2(w1), aB);
        aA = fdot2(yA[2], bch2(w2), aA); aB = fdot2(yB[2], bch2(w2), aB);
        aA = fdot2(yA[3], bch2(w3), aA); aB = fdot2(yB[3], bch2(w3), aB);
        aA = fdot2(yA[4], bch2(w4), aA); aB = fdot2(yB[4], bch2(w4), aB);
        aA = fdot2(yA[5], bch2(w5), aA); aB = fdot2(yB[5], bch2(w5), aB);
        aA = fdot2(yA[6], bch2(w6), aA); aB = fdot2(yB[6], bch2(w6), aB);

        float lfA = shr1_inf(SB);           // lane-1's SB; crosses half boundary:
        lfA = col0 ? INFV : lfA;            // forced to INFV at col 0 of each pair

        float SAold = SA;
        SA = smstep(SA, lfA, dgA, aA);      // cell A
        SB = smstep(SB, SA, SAold, aB);     // cell B (left=new SA, diag=old SA)
        dgA = lfA;
    }

    if (sj == 31) {                          // SB = R(63,63) of this half's pair
        const float r = SB * C_INV;
        simR[a * NSEQ + b] = r;
        simR[b * NSEQ + a] = r;
    }
}

// one wave per row: lse(row) - positive ; result parked in the (unused) diagonal
__global__ void row_lse(float* __restrict__ simR) {
    const int r = blockIdx.x;
    const int lane = threadIdx.x;
    const float* rowp = simR + r * NSEQ;
    float v0 = (lane == r) ? 0.f : 2.f * rowp[lane];
    const int c1 = lane + 64;
    float v1 = (c1 == r) ? 0.f : 2.f * rowp[c1];
    float mx = fmaxf(v0, v1);
#pragma unroll
    for (int o = 32; o; o >>= 1) mx = fmaxf(mx, __shfl_xor(mx, o));
    float s = __builtin_amdgcn_exp2f((v0 - mx) * 1.4426950408889634f)
            + __builtin_amdgcn_exp2f((v1 - mx) * 1.4426950408889634f);
#pragma unroll
    for (int o = 32; o; o >>= 1) s += __shfl_xor(s, o);
    if (lane == 0) {
        const int i = r & 63;
        float pos = 2.f * simR[i * NSEQ + i + 64];
        simR[r * NSEQ + r] = mx + 0.6931471805599453f * __builtin_amdgcn_logf(s) - pos;
    }
}

__global__ void final_loss(const float* __restrict__ simR, float* __restrict__ out) {
    __shared__ float red[NSEQ];
    const int tid = threadIdx.x;
    red[tid] = simR[tid * NSEQ + tid];
    __syncthreads();
    if (tid == 0) {
        float tsum = 0.f;
        for (int c = 0; c < NSEQ; c++) tsum += red[c];
        out[0] = tsum / (float)NSEQ;
    }
}

extern "C" void kernel_launch(void* const* d_in, const int* in_sizes, int n_in,
                              void* d_out, int out_size, void* d_ws, size_t ws_size,
                              hipStream_t stream) {
    const float* xxx = (const float*)d_in[0];
    const float* yyy = (const float*)d_in[1];
    float* out = (float*)d_out;
    float* simR = (float*)d_ws;   // 16384 floats = 64 KB

    sdtw_pairs<<<NWAVE / 4, 256, 0, stream>>>(xxx, yyy, simR);
    row_lse<<<NSEQ, 64, 0, stream>>>(simR);
    final_loss<<<1, NSEQ, 0, stream>>>(simR, out);
}